// Round 1
// 1006.825 us; speedup vs baseline: 1.0207x; 1.0207x over previous
//
#include <hip/hip_runtime.h>
#include <hip/hip_bf16.h>

// Problem constants (fixed by setup_inputs)
#define BB_  64
#define TT_  512
#define FF_  1024
#define HH_  31
#define GG_  124   // 4*H
#define FUT_ 16
#define TTOT_ 528  // T + future
#define OUT_ROW_ ((size_t)TTOT_ * FF_)   // per-batch stride in output

// ---- workspace layout (float indices) ----
#define PRE1_OFF ((size_t)0)                              // [512][64][128]
#define H2A_OFF  (PRE1_OFF + (size_t)TT_*64*128)          // [528*64][32]
#define WT_OFF   (H2A_OFF  + (size_t)TTOT_*64*32)         // [31][1024]
#define MV_OFF   (WT_OFF   + 31*1024)                     // [124][32]

__device__ __forceinline__ float rdlane(float v, int k) {
    return __uint_as_float(__builtin_amdgcn_readlane(__float_as_uint(v), k));
}

// ---------------- K0: transpose W_lin [1024][31] -> WT [31][1024] ----------------
__global__ void k0_prep(const float* __restrict__ Wlin, float* __restrict__ WT) {
    int i = blockIdx.x * 256 + threadIdx.x;   // 124*256 = 31744 = 1024*31 exactly
    int j = i / 31;
    int k = i - j * 31;
    WT[k * 1024 + j] = Wlin[i];
}

// ---------------- K0b: Mv[g][k] = sum_j Wih1[g][j]*Wlin[j][k]  (k=31 -> blin) ----------------
__global__ __launch_bounds__(64) void k0b_mv(
    const float* __restrict__ Wih1, const float* __restrict__ Wlin,
    const float* __restrict__ blin, float* __restrict__ Mv)
{
    int i = blockIdx.x * 64 + threadIdx.x;   // 62*64 = 3968 = 124*32
    int g = i >> 5, k = i & 31;
    const float* wr = Wih1 + (size_t)g * FF_;
    float acc = 0.0f;
    if (k < 31) {
#pragma unroll 8
        for (int j = 0; j < FF_; j++) acc += wr[j] * Wlin[j * 31 + k];
    } else {
#pragma unroll 8
        for (int j = 0; j < FF_; j++) acc += wr[j] * blin[j];
    }
    Mv[i] = acc;
}

// ---------------- K1: pregate GEMM: pre1[t][b][g] = x[b][t] . Wih1[g] + b1 ----------------
__global__ __launch_bounds__(256) void k1_pregate(
    const float* __restrict__ X,      // [B][T][F] fp32
    const float* __restrict__ Wih1,   // [G][F] fp32
    const float* __restrict__ bih1,
    const float* __restrict__ bhh1,
    float* __restrict__ pre1)         // [T][B][128]
{
    __shared__ __align__(16) float xs[32][64];    // [k][row]
    __shared__ __align__(16) float ws[32][128];   // [k][col]
    const int tid  = threadIdx.x;
    const int t    = blockIdx.x;
    const int tcol = tid & 31, trow = tid >> 5;
    const int c0 = tcol * 4, r0 = trow * 8;

    float4 acc[8];
#pragma unroll
    for (int r = 0; r < 8; r++) acc[r] = make_float4(0.f, 0.f, 0.f, 0.f);

    for (int kc = 0; kc < 32; ++kc) {
        const int k0 = kc * 32;
#pragma unroll
        for (int p = 0; p < 2; p++) {
            int i = tid + p * 256;
            int r = i >> 3, f = i & 7;
            float4 v = *(const float4*)(X + (size_t)r * TT_ * FF_ + (size_t)t * FF_ + k0 + f * 4);
            xs[f * 4 + 0][r] = v.x; xs[f * 4 + 1][r] = v.y;
            xs[f * 4 + 2][r] = v.z; xs[f * 4 + 3][r] = v.w;
        }
#pragma unroll
        for (int p = 0; p < 4; p++) {
            int i = tid + p * 256;
            int g = i >> 3, f = i & 7;
            float4 v = make_float4(0.f, 0.f, 0.f, 0.f);
            if (g < GG_) v = *(const float4*)(Wih1 + (size_t)g * FF_ + k0 + f * 4);
            ws[f * 4 + 0][g] = v.x; ws[f * 4 + 1][g] = v.y;
            ws[f * 4 + 2][g] = v.z; ws[f * 4 + 3][g] = v.w;
        }
        __syncthreads();
#pragma unroll
        for (int k = 0; k < 32; k++) {
            float4 wv = *(const float4*)&ws[k][c0];
            float4 xa = *(const float4*)&xs[k][r0];
            float4 xb = *(const float4*)&xs[k][r0 + 4];
            float rx[8] = {xa.x, xa.y, xa.z, xa.w, xb.x, xb.y, xb.z, xb.w};
#pragma unroll
            for (int r = 0; r < 8; r++) {
                acc[r].x += rx[r] * wv.x; acc[r].y += rx[r] * wv.y;
                acc[r].z += rx[r] * wv.z; acc[r].w += rx[r] * wv.w;
            }
        }
        __syncthreads();
    }
    float bias[4];
#pragma unroll
    for (int cc = 0; cc < 4; cc++) {
        int c = c0 + cc;
        bias[cc] = (c < GG_) ? (bih1[c] + bhh1[c]) : 0.0f;
    }
#pragma unroll
    for (int r = 0; r < 8; r++) {
        int m = t * 64 + r0 + r;
        float4 o = acc[r];
        o.x += bias[0]; o.y += bias[1]; o.z += bias[2]; o.w += bias[3];
        *(float4*)(pre1 + (size_t)m * 128 + c0) = o;
    }
}

// ---------------- K2: sequential recurrence, TWO WAVES per batch, 1 gate per lane ----------------
// 128 threads: thread L owns gate L (L<124; lanes 124-127 are padding that computes a
// dummy gate and is never read). Gate order: i:0-30, f:31-61, g:62-92, o:93-123.
// State owners: lane j = (L&63) < 31 of EACH wave redundantly compute h1/c1/h2/c2 so
// readlane() broadcast of h stays within-wave. Gate values cross waves via LDS + barrier.
// Per-lane weight footprint: 93 floats (3 rows of 31) -> fits in arch VGPRs, no AGPR
// round-trips / spill (the 64-thread version needed 186 floats vs VGPR_Count=136).
// Arithmetic order is textually identical to the previous version -> bit-identical output.
__global__ __launch_bounds__(128, 1) void k2_recur(
    const float* __restrict__ pre1,   // [T][B][128]  (bias already folded in)
    const float* __restrict__ Whh1,   // [G][H]
    const float* __restrict__ Wih2,   // [G][H]
    const float* __restrict__ Whh2,   // [G][H]
    const float* __restrict__ bih1, const float* __restrict__ bhh1,
    const float* __restrict__ bih2, const float* __restrict__ bhh2,
    const float* __restrict__ Mv,     // [124][32]  (M | v)
    float* __restrict__ h2a)          // [528*64][32]
{
    __shared__ float gsh1[128];       // layer-1 activated gates
    __shared__ float gsh2[128];       // layer-2 activated gates
    const int L  = threadIdx.x;       // 0..127
    const int bb = blockIdx.x;
    const int j  = L & 63;            // in-wave lane
    const int gc = (L < GG_) ? L : (GG_ - 1);   // clamped gate id for safe weight loads
    const bool isg = (gc >= 62 && gc < 93);     // tanh gate?
    const bool own = (j < HH_);                 // state-owner lane (both waves)

    // recurrent weights in registers: row gc of each [124][31] matrix (93 floats)
    float w1[31], wi2[31], wh2[31];
#pragma unroll
    for (int k = 0; k < 31; k++) {
        w1[k]  = Whh1[gc * 31 + k];
        wi2[k] = Wih2[gc * 31 + k];
        wh2[k] = Whh2[gc * 31 + k];
    }
    const float b2c = bih2[gc] + bhh2[gc];

    float hv1 = 0.0f, cv1 = 0.0f, hv2 = 0.0f, cv2 = 0.0f;

    // prefetch first pregate (lanes 124-127 read the zero-padded columns)
    float p = pre1[(size_t)bb * 128 + L];

    for (int t = 0; t < TT_; t++) {
        const float cur = p;
        if (t + 1 < TT_) {
            p = pre1[((size_t)(t + 1) * 64 + bb) * 128 + L];
        }
        // ---- layer 1 gate (serial accumulation, same order as before) ----
        float a = cur;
#pragma unroll
        for (int k = 0; k < 31; k++) {
            float hk = rdlane(hv1, k);
            a += w1[k] * hk;
        }
        {
            float z = isg ? (2.0f * a) : a;
            float s = 1.0f / (1.0f + __expf(-z));
            float act = isg ? (2.0f * s - 1.0f) : s;
            gsh1[L] = act;
        }
        __syncthreads();
        if (own) {
            float ig = gsh1[j];
            float fg = gsh1[j + 31];
            float gg = gsh1[j + 62];
            float og = gsh1[j + 93];
            cv1 = fg * cv1 + ig * gg;
            float e = __expf(-2.0f * cv1);
            hv1 = og * (2.0f / (1.0f + e) - 1.0f);
        }
        // ---- layer 2 gate ----
        float b = b2c;
#pragma unroll
        for (int k = 0; k < 31; k++) {
            float h1k = rdlane(hv1, k);
            float h2k = rdlane(hv2, k);
            b += wi2[k] * h1k + wh2[k] * h2k;
        }
        {
            float z = isg ? (2.0f * b) : b;
            float s = 1.0f / (1.0f + __expf(-z));
            float act = isg ? (2.0f * s - 1.0f) : s;
            gsh2[L] = act;
        }
        __syncthreads();
        if (own) {
            float ig = gsh2[j];
            float fg = gsh2[j + 31];
            float gg = gsh2[j + 62];
            float og = gsh2[j + 93];
            cv2 = fg * cv2 + ig * gg;
            float e = __expf(-2.0f * cv2);
            hv2 = og * (2.0f / (1.0f + e) - 1.0f);
        }
        if (L < HH_) h2a[((size_t)t * 64 + bb) * 32 + L] = hv2;   // wave-0 owners only
    }

    // ---- autoregressive future: pregate = M*h2 + v + b1 (1024-dot eliminated) ----
    float m[32];
#pragma unroll
    for (int k = 0; k < 32; k++) m[k] = Mv[gc * 32 + k];
    const float b1c = bih1[gc] + bhh1[gc];

    for (int sft = 0; sft < FUT_; sft++) {
        float a = b1c + m[31];   // + v[gc]
#pragma unroll
        for (int k = 0; k < 31; k++) {
            float h2k = rdlane(hv2, k);
            a += m[k] * h2k;
        }
#pragma unroll
        for (int k = 0; k < 31; k++) {
            float hk = rdlane(hv1, k);
            a += w1[k] * hk;
        }
        {
            float z = isg ? (2.0f * a) : a;
            float s = 1.0f / (1.0f + __expf(-z));
            float act = isg ? (2.0f * s - 1.0f) : s;
            gsh1[L] = act;
        }
        __syncthreads();
        if (own) {
            float ig = gsh1[j];
            float fg = gsh1[j + 31];
            float gg = gsh1[j + 62];
            float og = gsh1[j + 93];
            cv1 = fg * cv1 + ig * gg;
            float e = __expf(-2.0f * cv1);
            hv1 = og * (2.0f / (1.0f + e) - 1.0f);
        }
        float b = b2c;
#pragma unroll
        for (int k = 0; k < 31; k++) {
            float h1k = rdlane(hv1, k);
            float h2k = rdlane(hv2, k);
            b += wi2[k] * h1k + wh2[k] * h2k;
        }
        {
            float z = isg ? (2.0f * b) : b;
            float s = 1.0f / (1.0f + __expf(-z));
            float act = isg ? (2.0f * s - 1.0f) : s;
            gsh2[L] = act;
        }
        __syncthreads();
        if (own) {
            float ig = gsh2[j];
            float fg = gsh2[j + 31];
            float gg = gsh2[j + 62];
            float og = gsh2[j + 93];
            cv2 = fg * cv2 + ig * gg;
            float e = __expf(-2.0f * cv2);
            hv2 = og * (2.0f / (1.0f + e) - 1.0f);
        }
        if (L < HH_) h2a[((size_t)(TT_ + sft) * 64 + bb) * 32 + L] = hv2;
    }
}

// ---------------- K3: output linear for ALL 528 steps: out[b][t][:] = h2 . WT + b ----------------
__global__ __launch_bounds__(256) void k3_outlin(
    const float* __restrict__ h2a,   // [528*64][32]
    const float* __restrict__ WT,    // [31][1024]
    const float* __restrict__ blin,  // [1024]
    float* __restrict__ out)         // [B][528][1024] fp32
{
    __shared__ __align__(16) float hl[16][32];
    const int tid = threadIdx.x;
    const int m0  = blockIdx.x * 16;
#pragma unroll
    for (int p = 0; p < 2; p++) {
        int i = tid + p * 256;
        int r = i >> 5, k = i & 31;
        hl[r][k] = h2a[(size_t)(m0 + r) * 32 + k];
    }
    __syncthreads();
    const int c0 = tid * 4;
    float4 bl = *(const float4*)(blin + c0);
    float4 acc[16];
#pragma unroll
    for (int r = 0; r < 16; r++) acc[r] = bl;
    for (int k = 0; k < 31; k++) {
        float4 wv = *(const float4*)(WT + k * 1024 + c0);
#pragma unroll
        for (int r = 0; r < 16; r++) {
            float h = hl[r][k];
            acc[r].x += h * wv.x; acc[r].y += h * wv.y;
            acc[r].z += h * wv.z; acc[r].w += h * wv.w;
        }
    }
    const int t  = m0 >> 6;
    const int b0 = m0 & 63;
#pragma unroll
    for (int r = 0; r < 16; r++) {
        int b = b0 + r;
        *(float4*)(out + (size_t)b * OUT_ROW_ + (size_t)t * FF_ + c0) = acc[r];
    }
}

extern "C" void kernel_launch(void* const* d_in, const int* in_sizes, int n_in,
                              void* d_out, int out_size, void* d_ws, size_t ws_size,
                              hipStream_t stream) {
    (void)in_sizes; (void)n_in; (void)out_size; (void)ws_size;
    const float* X    = (const float*)d_in[0];
    const float* Wih1 = (const float*)d_in[1];
    const float* Whh1 = (const float*)d_in[2];
    const float* bih1 = (const float*)d_in[3];
    const float* bhh1 = (const float*)d_in[4];
    const float* Wih2 = (const float*)d_in[5];
    const float* Whh2 = (const float*)d_in[6];
    const float* bih2 = (const float*)d_in[7];
    const float* bhh2 = (const float*)d_in[8];
    const float* Wlin = (const float*)d_in[9];
    const float* blin = (const float*)d_in[10];
    // d_in[11] = future = 16 (constant for this problem)

    float* ws   = (float*)d_ws;
    float* pre1 = ws + PRE1_OFF;
    float* h2a  = ws + H2A_OFF;
    float* WT   = ws + WT_OFF;
    float* Mv   = ws + MV_OFF;
    float* out  = (float*)d_out;

    hipLaunchKernelGGL(k0_prep,    dim3(124),  dim3(256), 0, stream, Wlin, WT);
    hipLaunchKernelGGL(k0b_mv,     dim3(62),   dim3(64),  0, stream, Wih1, Wlin, blin, Mv);
    hipLaunchKernelGGL(k1_pregate, dim3(TT_),  dim3(256), 0, stream, X, Wih1, bih1, bhh1, pre1);
    hipLaunchKernelGGL(k2_recur,   dim3(BB_),  dim3(128), 0, stream, pre1, Whh1, Wih2, Whh2,
                       bih1, bhh1, bih2, bhh2, Mv, h2a);
    hipLaunchKernelGGL(k3_outlin,  dim3(TTOT_*4), dim3(256), 0, stream, h2a, WT, blin, out);
}

// Round 2
// 835.430 us; speedup vs baseline: 1.2302x; 1.2052x over previous
//
#include <hip/hip_runtime.h>
#include <hip/hip_bf16.h>

// Problem constants (fixed by setup_inputs)
#define BB_  64
#define TT_  512
#define FF_  1024
#define HH_  31
#define GG_  124   // 4*H
#define FUT_ 16
#define TTOT_ 528  // T + future
#define OUT_ROW_ ((size_t)TTOT_ * FF_)   // per-batch stride in output

// ---- workspace layout (float indices) ----
#define PRE1_OFF ((size_t)0)                              // [512][64][128]
#define H2A_OFF  (PRE1_OFF + (size_t)TT_*64*128)          // [528*64][32]
#define WT_OFF   (H2A_OFF  + (size_t)TTOT_*64*32)         // [31][1024]
#define MV_OFF   (WT_OFF   + 31*1024)                     // [124][32]

__device__ __forceinline__ float rdlane(float v, int k) {
    return __uint_as_float(__builtin_amdgcn_readlane(__float_as_uint(v), k));
}

// ---------------- K0: transpose W_lin [1024][31] -> WT [31][1024] ----------------
__global__ void k0_prep(const float* __restrict__ Wlin, float* __restrict__ WT) {
    int i = blockIdx.x * 256 + threadIdx.x;   // 124*256 = 31744 = 1024*31 exactly
    int j = i / 31;
    int k = i - j * 31;
    WT[k * 1024 + j] = Wlin[i];
}

// ---------------- K0b: Mv[g][k] = sum_j Wih1[g][j]*Wlin[j][k]  (k=31 -> blin) ----------------
__global__ __launch_bounds__(64) void k0b_mv(
    const float* __restrict__ Wih1, const float* __restrict__ Wlin,
    const float* __restrict__ blin, float* __restrict__ Mv)
{
    int i = blockIdx.x * 64 + threadIdx.x;   // 62*64 = 3968 = 124*32
    int g = i >> 5, k = i & 31;
    const float* wr = Wih1 + (size_t)g * FF_;
    float acc = 0.0f;
    if (k < 31) {
#pragma unroll 8
        for (int j = 0; j < FF_; j++) acc += wr[j] * Wlin[j * 31 + k];
    } else {
#pragma unroll 8
        for (int j = 0; j < FF_; j++) acc += wr[j] * blin[j];
    }
    Mv[i] = acc;
}

// ---------------- K1: pregate GEMM: pre1[t][b][g] = x[b][t] . Wih1[g] + b1 ----------------
__global__ __launch_bounds__(256) void k1_pregate(
    const float* __restrict__ X,      // [B][T][F] fp32
    const float* __restrict__ Wih1,   // [G][F] fp32
    const float* __restrict__ bih1,
    const float* __restrict__ bhh1,
    float* __restrict__ pre1)         // [T][B][128]
{
    __shared__ __align__(16) float xs[32][64];    // [k][row]
    __shared__ __align__(16) float ws[32][128];   // [k][col]
    const int tid  = threadIdx.x;
    const int t    = blockIdx.x;
    const int tcol = tid & 31, trow = tid >> 5;
    const int c0 = tcol * 4, r0 = trow * 8;

    float4 acc[8];
#pragma unroll
    for (int r = 0; r < 8; r++) acc[r] = make_float4(0.f, 0.f, 0.f, 0.f);

    for (int kc = 0; kc < 32; ++kc) {
        const int k0 = kc * 32;
#pragma unroll
        for (int p = 0; p < 2; p++) {
            int i = tid + p * 256;
            int r = i >> 3, f = i & 7;
            float4 v = *(const float4*)(X + (size_t)r * TT_ * FF_ + (size_t)t * FF_ + k0 + f * 4);
            xs[f * 4 + 0][r] = v.x; xs[f * 4 + 1][r] = v.y;
            xs[f * 4 + 2][r] = v.z; xs[f * 4 + 3][r] = v.w;
        }
#pragma unroll
        for (int p = 0; p < 4; p++) {
            int i = tid + p * 256;
            int g = i >> 3, f = i & 7;
            float4 v = make_float4(0.f, 0.f, 0.f, 0.f);
            if (g < GG_) v = *(const float4*)(Wih1 + (size_t)g * FF_ + k0 + f * 4);
            ws[f * 4 + 0][g] = v.x; ws[f * 4 + 1][g] = v.y;
            ws[f * 4 + 2][g] = v.z; ws[f * 4 + 3][g] = v.w;
        }
        __syncthreads();
#pragma unroll
        for (int k = 0; k < 32; k++) {
            float4 wv = *(const float4*)&ws[k][c0];
            float4 xa = *(const float4*)&xs[k][r0];
            float4 xb = *(const float4*)&xs[k][r0 + 4];
            float rx[8] = {xa.x, xa.y, xa.z, xa.w, xb.x, xb.y, xb.z, xb.w};
#pragma unroll
            for (int r = 0; r < 8; r++) {
                acc[r].x += rx[r] * wv.x; acc[r].y += rx[r] * wv.y;
                acc[r].z += rx[r] * wv.z; acc[r].w += rx[r] * wv.w;
            }
        }
        __syncthreads();
    }
    float bias[4];
#pragma unroll
    for (int cc = 0; cc < 4; cc++) {
        int c = c0 + cc;
        bias[cc] = (c < GG_) ? (bih1[c] + bhh1[c]) : 0.0f;
    }
#pragma unroll
    for (int r = 0; r < 8; r++) {
        int m = t * 64 + r0 + r;
        float4 o = acc[r];
        o.x += bias[0]; o.y += bias[1]; o.z += bias[2]; o.w += bias[3];
        *(float4*)(pre1 + (size_t)m * 128 + c0) = o;
    }
}

// ---------------- K2: sequential recurrence, merged-phase pipeline ----------------
// 128 threads, 1 gate per lane (gate order i:0-30, f:31-61, g:62-92, o:93-123;
// lanes 124-127 compute a dummy gate that is never read).
// State owners: lane j=(L&63)<31 of EACH wave redundantly keep h1/c1/h2/c2 so
// readlane() broadcast stays within-wave.
// Pipeline: prologue computes L1(0); each main iteration t computes L2(t) AND
// L1(t+1) in ONE gate phase (both need only h1(t)/h2(t-1)), sharing the h1
// readlanes, with a SINGLE barrier per step and double-buffered gate arrays.
// Weight rows are pinned into arch VGPRs via empty asm ("+v") so the compiler
// cannot rematerialize them from memory each step (round-1 VGPR_Count=72 showed
// the 93 weight floats were NOT register-resident -> per-step memory churn).
// All per-gate accumulation orders are textually identical to the verified
// 2-phase version -> bit-identical output.
__global__ __launch_bounds__(128, 1) void k2_recur(
    const float* __restrict__ pre1,   // [T][B][128]  (bias already folded in)
    const float* __restrict__ Whh1,   // [G][H]
    const float* __restrict__ Wih2,   // [G][H]
    const float* __restrict__ Whh2,   // [G][H]
    const float* __restrict__ bih1, const float* __restrict__ bhh1,
    const float* __restrict__ bih2, const float* __restrict__ bhh2,
    const float* __restrict__ Mv,     // [124][32]  (M | v)
    float* __restrict__ h2a)          // [528*64][32]
{
    __shared__ float gA[2][128];      // layer-1 activated gates (double-buffered)
    __shared__ float g2[2][128];      // layer-2 activated gates (double-buffered)
    const int L  = threadIdx.x;       // 0..127
    const int bb = blockIdx.x;
    const int j  = L & 63;            // in-wave lane
    const int gc = (L < GG_) ? L : (GG_ - 1);   // clamped gate id for safe loads
    const bool isg = (gc >= 62 && gc < 93);     // tanh gate?
    const bool own = (j < HH_);                 // state-owner lane (both waves)

    // recurrent weights in registers: row gc of each [124][31] matrix (93 floats)
    float w1[31], wi2[31], wh2[31];
#pragma unroll
    for (int k = 0; k < 31; k++) {
        w1[k]  = Whh1[gc * 31 + k];
        wi2[k] = Wih2[gc * 31 + k];
        wh2[k] = Whh2[gc * 31 + k];
    }
    // pin into arch VGPRs: opaque redefinition blocks remat-from-memory
#pragma unroll
    for (int k = 0; k < 31; k++) {
        asm volatile("" : "+v"(w1[k]), "+v"(wi2[k]), "+v"(wh2[k]));
    }
    const float b2c = bih2[gc] + bhh2[gc];

    float hv1 = 0.0f, cv1 = 0.0f, hv2 = 0.0f, cv2 = 0.0f;

    // ---- prologue: layer-1 gates for t=0 (hv1 == 0, adds exact zeros) ----
    float cur0 = pre1[(size_t)bb * 128 + L];
    float pnxt = pre1[((size_t)1 * 64 + bb) * 128 + L];   // p(1)
    {
        float a = cur0;
#pragma unroll
        for (int k = 0; k < 31; k++) {
            float hk = rdlane(hv1, k);
            a += w1[k] * hk;
        }
        float z = isg ? (2.0f * a) : a;
        float s = 1.0f / (1.0f + __expf(-z));
        gA[1][L] = isg ? (2.0f * s - 1.0f) : s;
    }
    __syncthreads();
    if (own) {
        float ig = gA[1][j];
        float fg = gA[1][j + 31];
        float gg = gA[1][j + 62];
        float og = gA[1][j + 93];
        cv1 = fg * cv1 + ig * gg;
        float e = __expf(-2.0f * cv1);
        hv1 = og * (2.0f / (1.0f + e) - 1.0f);   // h1(0)
    }

    // ---- main merged loop: iteration t computes L2(t) + L1(t+1), t = 0..510 ----
    for (int t = 0; t < TT_ - 1; t++) {
        const int pb = t & 1;
        const float cur = pnxt;          // p(t+1)
        float pld = 0.0f;
        if (t + 2 < TT_) pld = pre1[((size_t)(t + 2) * 64 + bb) * 128 + L];

        float b = b2c;                    // L2(t) pre-activation
        float a = cur;                    // L1(t+1) pre-activation
#pragma unroll
        for (int k = 0; k < 31; k++) {
            float h1k = rdlane(hv1, k);   // h1(t), shared by both dots
            float h2k = rdlane(hv2, k);   // h2(t-1)
            b += wi2[k] * h1k + wh2[k] * h2k;   // same order as verified version
            a += w1[k] * h1k;                    // same order as verified version
        }
        {
            float z = isg ? (2.0f * b) : b;
            float s = 1.0f / (1.0f + __expf(-z));
            g2[pb][L] = isg ? (2.0f * s - 1.0f) : s;
        }
        {
            float z = isg ? (2.0f * a) : a;
            float s = 1.0f / (1.0f + __expf(-z));
            gA[pb][L] = isg ? (2.0f * s - 1.0f) : s;
        }
        __syncthreads();
        if (own) {
            // layer-2 state update (h2(t))
            float ig = g2[pb][j];
            float fg = g2[pb][j + 31];
            float gg = g2[pb][j + 62];
            float og = g2[pb][j + 93];
            cv2 = fg * cv2 + ig * gg;
            float e = __expf(-2.0f * cv2);
            hv2 = og * (2.0f / (1.0f + e) - 1.0f);
            // layer-1 state update (h1(t+1))
            float i1 = gA[pb][j];
            float f1 = gA[pb][j + 31];
            float g1v = gA[pb][j + 62];
            float o1 = gA[pb][j + 93];
            cv1 = f1 * cv1 + i1 * g1v;
            float e1 = __expf(-2.0f * cv1);
            hv1 = o1 * (2.0f / (1.0f + e1) - 1.0f);
        }
        if (L < HH_) h2a[((size_t)t * 64 + bb) * 32 + L] = hv2;
        pnxt = pld;
    }

    // ---- tail: L2(511) only ----
    {
        float b = b2c;
#pragma unroll
        for (int k = 0; k < 31; k++) {
            float h1k = rdlane(hv1, k);   // h1(511)
            float h2k = rdlane(hv2, k);   // h2(510)
            b += wi2[k] * h1k + wh2[k] * h2k;
        }
        float z = isg ? (2.0f * b) : b;
        float s = 1.0f / (1.0f + __expf(-z));
        g2[1][L] = isg ? (2.0f * s - 1.0f) : s;   // 511&1==1; g2[0] reads done
    }
    __syncthreads();
    if (own) {
        float ig = g2[1][j];
        float fg = g2[1][j + 31];
        float gg = g2[1][j + 62];
        float og = g2[1][j + 93];
        cv2 = fg * cv2 + ig * gg;
        float e = __expf(-2.0f * cv2);
        hv2 = og * (2.0f / (1.0f + e) - 1.0f);    // h2(511)
    }
    if (L < HH_) h2a[((size_t)(TT_ - 1) * 64 + bb) * 32 + L] = hv2;

    // ---- autoregressive future: 2-phase structure (verified), M*h2 trick ----
    float m[32];
#pragma unroll
    for (int k = 0; k < 32; k++) m[k] = Mv[gc * 32 + k];
#pragma unroll
    for (int k = 0; k < 32; k++) asm volatile("" : "+v"(m[k]));
    const float b1c = bih1[gc] + bhh1[gc];

    for (int sft = 0; sft < FUT_; sft++) {
        float a = b1c + m[31];   // + v[gc]
#pragma unroll
        for (int k = 0; k < 31; k++) {
            float h2k = rdlane(hv2, k);
            a += m[k] * h2k;
        }
#pragma unroll
        for (int k = 0; k < 31; k++) {
            float hk = rdlane(hv1, k);
            a += w1[k] * hk;
        }
        {
            float z = isg ? (2.0f * a) : a;
            float s = 1.0f / (1.0f + __expf(-z));
            gA[0][L] = isg ? (2.0f * s - 1.0f) : s;
        }
        __syncthreads();
        if (own) {
            float ig = gA[0][j];
            float fg = gA[0][j + 31];
            float gg = gA[0][j + 62];
            float og = gA[0][j + 93];
            cv1 = fg * cv1 + ig * gg;
            float e = __expf(-2.0f * cv1);
            hv1 = og * (2.0f / (1.0f + e) - 1.0f);
        }
        float b = b2c;
#pragma unroll
        for (int k = 0; k < 31; k++) {
            float h1k = rdlane(hv1, k);
            float h2k = rdlane(hv2, k);
            b += wi2[k] * h1k + wh2[k] * h2k;
        }
        {
            float z = isg ? (2.0f * b) : b;
            float s = 1.0f / (1.0f + __expf(-z));
            g2[0][L] = isg ? (2.0f * s - 1.0f) : s;
        }
        __syncthreads();
        if (own) {
            float ig = g2[0][j];
            float fg = g2[0][j + 31];
            float gg = g2[0][j + 62];
            float og = g2[0][j + 93];
            cv2 = fg * cv2 + ig * gg;
            float e = __expf(-2.0f * cv2);
            hv2 = og * (2.0f / (1.0f + e) - 1.0f);
        }
        if (L < HH_) h2a[((size_t)(TT_ + sft) * 64 + bb) * 32 + L] = hv2;
    }
}

// ---------------- K3: output linear for ALL 528 steps: out[b][t][:] = h2 . WT + b ----------------
__global__ __launch_bounds__(256) void k3_outlin(
    const float* __restrict__ h2a,   // [528*64][32]
    const float* __restrict__ WT,    // [31][1024]
    const float* __restrict__ blin,  // [1024]
    float* __restrict__ out)         // [B][528][1024] fp32
{
    __shared__ __align__(16) float hl[16][32];
    const int tid = threadIdx.x;
    const int m0  = blockIdx.x * 16;
#pragma unroll
    for (int p = 0; p < 2; p++) {
        int i = tid + p * 256;
        int r = i >> 5, k = i & 31;
        hl[r][k] = h2a[(size_t)(m0 + r) * 32 + k];
    }
    __syncthreads();
    const int c0 = tid * 4;
    float4 bl = *(const float4*)(blin + c0);
    float4 acc[16];
#pragma unroll
    for (int r = 0; r < 16; r++) acc[r] = bl;
    for (int k = 0; k < 31; k++) {
        float4 wv = *(const float4*)(WT + k * 1024 + c0);
#pragma unroll
        for (int r = 0; r < 16; r++) {
            float h = hl[r][k];
            acc[r].x += h * wv.x; acc[r].y += h * wv.y;
            acc[r].z += h * wv.z; acc[r].w += h * wv.w;
        }
    }
    const int t  = m0 >> 6;
    const int b0 = m0 & 63;
#pragma unroll
    for (int r = 0; r < 16; r++) {
        int b = b0 + r;
        *(float4*)(out + (size_t)b * OUT_ROW_ + (size_t)t * FF_ + c0) = acc[r];
    }
}

extern "C" void kernel_launch(void* const* d_in, const int* in_sizes, int n_in,
                              void* d_out, int out_size, void* d_ws, size_t ws_size,
                              hipStream_t stream) {
    (void)in_sizes; (void)n_in; (void)out_size; (void)ws_size;
    const float* X    = (const float*)d_in[0];
    const float* Wih1 = (const float*)d_in[1];
    const float* Whh1 = (const float*)d_in[2];
    const float* bih1 = (const float*)d_in[3];
    const float* bhh1 = (const float*)d_in[4];
    const float* Wih2 = (const float*)d_in[5];
    const float* Whh2 = (const float*)d_in[6];
    const float* bih2 = (const float*)d_in[7];
    const float* bhh2 = (const float*)d_in[8];
    const float* Wlin = (const float*)d_in[9];
    const float* blin = (const float*)d_in[10];
    // d_in[11] = future = 16 (constant for this problem)

    float* ws   = (float*)d_ws;
    float* pre1 = ws + PRE1_OFF;
    float* h2a  = ws + H2A_OFF;
    float* WT   = ws + WT_OFF;
    float* Mv   = ws + MV_OFF;
    float* out  = (float*)d_out;

    hipLaunchKernelGGL(k0_prep,    dim3(124),  dim3(256), 0, stream, Wlin, WT);
    hipLaunchKernelGGL(k0b_mv,     dim3(62),   dim3(64),  0, stream, Wih1, Wlin, blin, Mv);
    hipLaunchKernelGGL(k1_pregate, dim3(TT_),  dim3(256), 0, stream, X, Wih1, bih1, bhh1, pre1);
    hipLaunchKernelGGL(k2_recur,   dim3(BB_),  dim3(128), 0, stream, pre1, Whh1, Wih2, Whh2,
                       bih1, bhh1, bih2, bhh2, Mv, h2a);
    hipLaunchKernelGGL(k3_outlin,  dim3(TTOT_*4), dim3(256), 0, stream, h2a, WT, blin, out);
}

// Round 3
// 832.072 us; speedup vs baseline: 1.2351x; 1.0040x over previous
//
#include <hip/hip_runtime.h>
#include <hip/hip_bf16.h>

// Problem constants (fixed by setup_inputs)
#define BB_  64
#define TT_  512
#define FF_  1024
#define HH_  31
#define GG_  124   // 4*H
#define FUT_ 16
#define TTOT_ 528  // T + future
#define OUT_ROW_ ((size_t)TTOT_ * FF_)   // per-batch stride in output

// ---- workspace layout (float indices) ----
#define PRE1_OFF ((size_t)0)                              // [512][64][128]
#define H2A_OFF  (PRE1_OFF + (size_t)TT_*64*128)          // [528*64][32]
#define WT_OFF   (H2A_OFF  + (size_t)TTOT_*64*32)         // [31][1024]
#define MV_OFF   (WT_OFF   + 31*1024)                     // [124][32]

__device__ __forceinline__ float rdlane(float v, int k) {
    return __uint_as_float(__builtin_amdgcn_readlane(__float_as_uint(v), k));
}

// repeat macro over k = 0..30
#define REP31(M) M(0) M(1) M(2) M(3) M(4) M(5) M(6) M(7) M(8) M(9) \
                 M(10) M(11) M(12) M(13) M(14) M(15) M(16) M(17) M(18) M(19) \
                 M(20) M(21) M(22) M(23) M(24) M(25) M(26) M(27) M(28) M(29) M(30)

// ---------------- K0: transpose W_lin [1024][31] -> WT [31][1024] ----------------
__global__ void k0_prep(const float* __restrict__ Wlin, float* __restrict__ WT) {
    int i = blockIdx.x * 256 + threadIdx.x;   // 124*256 = 31744 = 1024*31 exactly
    int j = i / 31;
    int k = i - j * 31;
    WT[k * 1024 + j] = Wlin[i];
}

// ---------------- K0b: Mv[g][k] = sum_j Wih1[g][j]*Wlin[j][k]  (k=31 -> blin) ----------------
__global__ __launch_bounds__(64) void k0b_mv(
    const float* __restrict__ Wih1, const float* __restrict__ Wlin,
    const float* __restrict__ blin, float* __restrict__ Mv)
{
    int i = blockIdx.x * 64 + threadIdx.x;   // 62*64 = 3968 = 124*32
    int g = i >> 5, k = i & 31;
    const float* wr = Wih1 + (size_t)g * FF_;
    float acc = 0.0f;
    if (k < 31) {
#pragma unroll 8
        for (int j = 0; j < FF_; j++) acc += wr[j] * Wlin[j * 31 + k];
    } else {
#pragma unroll 8
        for (int j = 0; j < FF_; j++) acc += wr[j] * blin[j];
    }
    Mv[i] = acc;
}

// ---------------- K1: pregate GEMM: pre1[t][b][g] = x[b][t] . Wih1[g] + b1 ----------------
__global__ __launch_bounds__(256) void k1_pregate(
    const float* __restrict__ X,      // [B][T][F] fp32
    const float* __restrict__ Wih1,   // [G][F] fp32
    const float* __restrict__ bih1,
    const float* __restrict__ bhh1,
    float* __restrict__ pre1)         // [T][B][128]
{
    __shared__ __align__(16) float xs[32][64];    // [k][row]
    __shared__ __align__(16) float ws[32][128];   // [k][col]
    const int tid  = threadIdx.x;
    const int t    = blockIdx.x;
    const int tcol = tid & 31, trow = tid >> 5;
    const int c0 = tcol * 4, r0 = trow * 8;

    float4 acc[8];
#pragma unroll
    for (int r = 0; r < 8; r++) acc[r] = make_float4(0.f, 0.f, 0.f, 0.f);

    for (int kc = 0; kc < 32; ++kc) {
        const int k0 = kc * 32;
#pragma unroll
        for (int p = 0; p < 2; p++) {
            int i = tid + p * 256;
            int r = i >> 3, f = i & 7;
            float4 v = *(const float4*)(X + (size_t)r * TT_ * FF_ + (size_t)t * FF_ + k0 + f * 4);
            xs[f * 4 + 0][r] = v.x; xs[f * 4 + 1][r] = v.y;
            xs[f * 4 + 2][r] = v.z; xs[f * 4 + 3][r] = v.w;
        }
#pragma unroll
        for (int p = 0; p < 4; p++) {
            int i = tid + p * 256;
            int g = i >> 3, f = i & 7;
            float4 v = make_float4(0.f, 0.f, 0.f, 0.f);
            if (g < GG_) v = *(const float4*)(Wih1 + (size_t)g * FF_ + k0 + f * 4);
            ws[f * 4 + 0][g] = v.x; ws[f * 4 + 1][g] = v.y;
            ws[f * 4 + 2][g] = v.z; ws[f * 4 + 3][g] = v.w;
        }
        __syncthreads();
#pragma unroll
        for (int k = 0; k < 32; k++) {
            float4 wv = *(const float4*)&ws[k][c0];
            float4 xa = *(const float4*)&xs[k][r0];
            float4 xb = *(const float4*)&xs[k][r0 + 4];
            float rx[8] = {xa.x, xa.y, xa.z, xa.w, xb.x, xb.y, xb.z, xb.w};
#pragma unroll
            for (int r = 0; r < 8; r++) {
                acc[r].x += rx[r] * wv.x; acc[r].y += rx[r] * wv.y;
                acc[r].z += rx[r] * wv.z; acc[r].w += rx[r] * wv.w;
            }
        }
        __syncthreads();
    }
    float bias[4];
#pragma unroll
    for (int cc = 0; cc < 4; cc++) {
        int c = c0 + cc;
        bias[cc] = (c < GG_) ? (bih1[c] + bhh1[c]) : 0.0f;
    }
#pragma unroll
    for (int r = 0; r < 8; r++) {
        int m = t * 64 + r0 + r;
        float4 o = acc[r];
        o.x += bias[0]; o.y += bias[1]; o.z += bias[2]; o.w += bias[3];
        *(float4*)(pre1 + (size_t)m * 128 + c0) = o;
    }
}

// ---------------- K2: sequential recurrence, merged-phase pipeline ----------------
// 128 threads, 1 gate per lane (gate order i:0-30, f:31-61, g:62-92, o:93-123;
// lanes 124-127 compute a dummy gate that is never read).
// State owners: lane j=(L&63)<31 of EACH wave redundantly keep h1/c1/h2/c2 so
// readlane() broadcast stays within-wave.
// Pipeline: prologue computes L1(0); each main iteration t computes L2(t) AND
// L1(t+1) in ONE gate phase (both need only h1(t)/h2(t-1)), sharing the h1
// readlanes, with a SINGLE barrier per step and double-buffered gate arrays.
// WEIGHT RESIDENCY: rounds 0-2 kept weights in local ARRAYS; the compiler
// only partially scalar-replaced them (VGPR_Count 136/72/72 vs 186/93/93
// floats needed) and spilled the rest to scratch -> ~550 issued insts/step
// (measured via VALUBusy*dur). This version uses 93 individually NAMED
// scalars + macro-unrolled dots so SROA is trivial and the allocator can
// keep every weight in an arch VGPR (budget 256 at 1 block/CU).
// All per-gate accumulation expressions are textually identical to the
// verified round-2 version -> bit-identical output.
__global__ __launch_bounds__(128, 1) void k2_recur(
    const float* __restrict__ pre1,   // [T][B][128]  (bias already folded in)
    const float* __restrict__ Whh1,   // [G][H]
    const float* __restrict__ Wih2,   // [G][H]
    const float* __restrict__ Whh2,   // [G][H]
    const float* __restrict__ bih1, const float* __restrict__ bhh1,
    const float* __restrict__ bih2, const float* __restrict__ bhh2,
    const float* __restrict__ Mv,     // [124][32]  (M | v)
    float* __restrict__ h2a)          // [528*64][32]
{
    __shared__ float gA[2][128];      // layer-1 activated gates (double-buffered)
    __shared__ float g2[2][128];      // layer-2 activated gates (double-buffered)
    const int L  = threadIdx.x;       // 0..127
    const int bb = blockIdx.x;
    const int j  = L & 63;            // in-wave lane
    const int gc = (L < GG_) ? L : (GG_ - 1);   // clamped gate id for safe loads
    const bool isg = (gc >= 62 && gc < 93);     // tanh gate?
    const bool own = (j < HH_);                 // state-owner lane (both waves)

    // recurrent weights as NAMED scalars: row gc of each [124][31] matrix
#define WLOAD(k) float w1_##k  = Whh1[gc * 31 + k]; \
                 float wi2_##k = Wih2[gc * 31 + k]; \
                 float wh2_##k = Whh2[gc * 31 + k];
    REP31(WLOAD)
#undef WLOAD

    const float b2c = bih2[gc] + bhh2[gc];

    float hv1 = 0.0f, cv1 = 0.0f, hv2 = 0.0f, cv2 = 0.0f;

    // ---- prologue: layer-1 gates for t=0 (hv1 == 0, adds exact zeros) ----
    float cur0 = pre1[(size_t)bb * 128 + L];
    float pnxt = pre1[((size_t)1 * 64 + bb) * 128 + L];   // p(1)
    {
        float a = cur0;
#define DOTP(k) { float hk = rdlane(hv1, k); a += w1_##k * hk; }
        REP31(DOTP)
#undef DOTP
        float z = isg ? (2.0f * a) : a;
        float s = 1.0f / (1.0f + __expf(-z));
        gA[1][L] = isg ? (2.0f * s - 1.0f) : s;
    }
    __syncthreads();
    if (own) {
        float ig = gA[1][j];
        float fg = gA[1][j + 31];
        float gg = gA[1][j + 62];
        float og = gA[1][j + 93];
        cv1 = fg * cv1 + ig * gg;
        float e = __expf(-2.0f * cv1);
        hv1 = og * (2.0f / (1.0f + e) - 1.0f);   // h1(0)
    }

    // ---- main merged loop: iteration t computes L2(t) + L1(t+1), t = 0..510 ----
    for (int t = 0; t < TT_ - 1; t++) {
        const int pb = t & 1;
        const float cur = pnxt;          // p(t+1)
        float pld = 0.0f;
        if (t + 2 < TT_) pld = pre1[((size_t)(t + 2) * 64 + bb) * 128 + L];

        float b = b2c;                    // L2(t) pre-activation
        float a = cur;                    // L1(t+1) pre-activation
#define DOTM(k) { float h1k = rdlane(hv1, k); float h2k = rdlane(hv2, k); \
                  b += wi2_##k * h1k + wh2_##k * h2k; \
                  a += w1_##k * h1k; }
        REP31(DOTM)
#undef DOTM
        {
            float z = isg ? (2.0f * b) : b;
            float s = 1.0f / (1.0f + __expf(-z));
            g2[pb][L] = isg ? (2.0f * s - 1.0f) : s;
        }
        {
            float z = isg ? (2.0f * a) : a;
            float s = 1.0f / (1.0f + __expf(-z));
            gA[pb][L] = isg ? (2.0f * s - 1.0f) : s;
        }
        __syncthreads();
        if (own) {
            // layer-2 state update (h2(t))
            float ig = g2[pb][j];
            float fg = g2[pb][j + 31];
            float gg = g2[pb][j + 62];
            float og = g2[pb][j + 93];
            cv2 = fg * cv2 + ig * gg;
            float e = __expf(-2.0f * cv2);
            hv2 = og * (2.0f / (1.0f + e) - 1.0f);
            // layer-1 state update (h1(t+1))
            float i1 = gA[pb][j];
            float f1 = gA[pb][j + 31];
            float g1v = gA[pb][j + 62];
            float o1 = gA[pb][j + 93];
            cv1 = f1 * cv1 + i1 * g1v;
            float e1 = __expf(-2.0f * cv1);
            hv1 = o1 * (2.0f / (1.0f + e1) - 1.0f);
        }
        if (L < HH_) h2a[((size_t)t * 64 + bb) * 32 + L] = hv2;
        pnxt = pld;
    }

    // ---- tail: L2(511) only ----
    {
        float b = b2c;
#define DOTT(k) { float h1k = rdlane(hv1, k); float h2k = rdlane(hv2, k); \
                  b += wi2_##k * h1k + wh2_##k * h2k; }
        REP31(DOTT)
#undef DOTT
        float z = isg ? (2.0f * b) : b;
        float s = 1.0f / (1.0f + __expf(-z));
        g2[1][L] = isg ? (2.0f * s - 1.0f) : s;   // 511&1==1; g2[0] reads done
    }
    __syncthreads();
    if (own) {
        float ig = g2[1][j];
        float fg = g2[1][j + 31];
        float gg = g2[1][j + 62];
        float og = g2[1][j + 93];
        cv2 = fg * cv2 + ig * gg;
        float e = __expf(-2.0f * cv2);
        hv2 = og * (2.0f / (1.0f + e) - 1.0f);    // h2(511)
    }
    if (L < HH_) h2a[((size_t)(TT_ - 1) * 64 + bb) * 32 + L] = hv2;

    // ---- autoregressive future: 2-phase structure (verified), M*h2 trick ----
#define MLOAD(k) float m_##k = Mv[gc * 32 + k];
    REP31(MLOAD)
#undef MLOAD
    float m_31 = Mv[gc * 32 + 31];
    const float b1c = bih1[gc] + bhh1[gc];

    for (int sft = 0; sft < FUT_; sft++) {
        float a = b1c + m_31;   // + v[gc]
#define DOTF1(k) { float h2k = rdlane(hv2, k); a += m_##k * h2k; }
        REP31(DOTF1)
#undef DOTF1
#define DOTF2(k) { float hk = rdlane(hv1, k); a += w1_##k * hk; }
        REP31(DOTF2)
#undef DOTF2
        {
            float z = isg ? (2.0f * a) : a;
            float s = 1.0f / (1.0f + __expf(-z));
            gA[0][L] = isg ? (2.0f * s - 1.0f) : s;
        }
        __syncthreads();
        if (own) {
            float ig = gA[0][j];
            float fg = gA[0][j + 31];
            float gg = gA[0][j + 62];
            float og = gA[0][j + 93];
            cv1 = fg * cv1 + ig * gg;
            float e = __expf(-2.0f * cv1);
            hv1 = og * (2.0f / (1.0f + e) - 1.0f);
        }
        float b = b2c;
#define DOTF3(k) { float h1k = rdlane(hv1, k); float h2k = rdlane(hv2, k); \
                   b += wi2_##k * h1k + wh2_##k * h2k; }
        REP31(DOTF3)
#undef DOTF3
        {
            float z = isg ? (2.0f * b) : b;
            float s = 1.0f / (1.0f + __expf(-z));
            g2[0][L] = isg ? (2.0f * s - 1.0f) : s;
        }
        __syncthreads();
        if (own) {
            float ig = g2[0][j];
            float fg = g2[0][j + 31];
            float gg = g2[0][j + 62];
            float og = g2[0][j + 93];
            cv2 = fg * cv2 + ig * gg;
            float e = __expf(-2.0f * cv2);
            hv2 = og * (2.0f / (1.0f + e) - 1.0f);
        }
        if (L < HH_) h2a[((size_t)(TT_ + sft) * 64 + bb) * 32 + L] = hv2;
    }
}

// ---------------- K3: output linear for ALL 528 steps: out[b][t][:] = h2 . WT + b ----------------
__global__ __launch_bounds__(256) void k3_outlin(
    const float* __restrict__ h2a,   // [528*64][32]
    const float* __restrict__ WT,    // [31][1024]
    const float* __restrict__ blin,  // [1024]
    float* __restrict__ out)         // [B][528][1024] fp32
{
    __shared__ __align__(16) float hl[16][32];
    const int tid = threadIdx.x;
    const int m0  = blockIdx.x * 16;
#pragma unroll
    for (int p = 0; p < 2; p++) {
        int i = tid + p * 256;
        int r = i >> 5, k = i & 31;
        hl[r][k] = h2a[(size_t)(m0 + r) * 32 + k];
    }
    __syncthreads();
    const int c0 = tid * 4;
    float4 bl = *(const float4*)(blin + c0);
    float4 acc[16];
#pragma unroll
    for (int r = 0; r < 16; r++) acc[r] = bl;
    for (int k = 0; k < 31; k++) {
        float4 wv = *(const float4*)(WT + k * 1024 + c0);
#pragma unroll
        for (int r = 0; r < 16; r++) {
            float h = hl[r][k];
            acc[r].x += h * wv.x; acc[r].y += h * wv.y;
            acc[r].z += h * wv.z; acc[r].w += h * wv.w;
        }
    }
    const int t  = m0 >> 6;
    const int b0 = m0 & 63;
#pragma unroll
    for (int r = 0; r < 16; r++) {
        int b = b0 + r;
        *(float4*)(out + (size_t)b * OUT_ROW_ + (size_t)t * FF_ + c0) = acc[r];
    }
}

extern "C" void kernel_launch(void* const* d_in, const int* in_sizes, int n_in,
                              void* d_out, int out_size, void* d_ws, size_t ws_size,
                              hipStream_t stream) {
    (void)in_sizes; (void)n_in; (void)out_size; (void)ws_size;
    const float* X    = (const float*)d_in[0];
    const float* Wih1 = (const float*)d_in[1];
    const float* Whh1 = (const float*)d_in[2];
    const float* bih1 = (const float*)d_in[3];
    const float* bhh1 = (const float*)d_in[4];
    const float* Wih2 = (const float*)d_in[5];
    const float* Whh2 = (const float*)d_in[6];
    const float* bih2 = (const float*)d_in[7];
    const float* bhh2 = (const float*)d_in[8];
    const float* Wlin = (const float*)d_in[9];
    const float* blin = (const float*)d_in[10];
    // d_in[11] = future = 16 (constant for this problem)

    float* ws   = (float*)d_ws;
    float* pre1 = ws + PRE1_OFF;
    float* h2a  = ws + H2A_OFF;
    float* WT   = ws + WT_OFF;
    float* Mv   = ws + MV_OFF;
    float* out  = (float*)d_out;

    hipLaunchKernelGGL(k0_prep,    dim3(124),  dim3(256), 0, stream, Wlin, WT);
    hipLaunchKernelGGL(k0b_mv,     dim3(62),   dim3(64),  0, stream, Wih1, Wlin, blin, Mv);
    hipLaunchKernelGGL(k1_pregate, dim3(TT_),  dim3(256), 0, stream, X, Wih1, bih1, bhh1, pre1);
    hipLaunchKernelGGL(k2_recur,   dim3(BB_),  dim3(128), 0, stream, pre1, Whh1, Wih2, Whh2,
                       bih1, bhh1, bih2, bhh2, Mv, h2a);
    hipLaunchKernelGGL(k3_outlin,  dim3(TTOT_*4), dim3(256), 0, stream, h2a, WT, blin, out);
}